// Round 16
// baseline (39.740 us; speedup 1.0000x reference)
//
#include <hip/hip_runtime.h>
#include <stdint.h>

typedef _Float16 f16;
typedef _Float16 f16x8 __attribute__((ext_vector_type(8)));
typedef float f32x4 __attribute__((ext_vector_type(4)));

#define LQn   2048
#define LKVn  1024
#define DM    512
#define NH    8
#define WSZ   262144   // f16 elems per packed weight matrix (512 KB)

static __device__ __forceinline__ f32x4 mfma_f16(f16x8 a, f16x8 b, f32x4 c) {
  return __builtin_amdgcn_mfma_f32_16x16x32_f16(a, b, c, 0, 0, 0);
}

// ---------- weight transpose + convert + FRAGMENT-PACK (unchanged).
__global__ __launch_bounds__(256) void transpose_w_kernel(
    const float* __restrict__ Wq, const float* __restrict__ Wk,
    const float* __restrict__ Wv, const float* __restrict__ Wo,
    f16* __restrict__ WTf) {
  __shared__ float tile[64 * 65];
  const int bid = blockIdx.x;
  const int mat = bid >> 6;
  const int tb  = bid & 63;
  const int r0 = (tb >> 3) * 64;  // k block
  const int c0 = (tb & 7) * 64;   // n block
  const float* W = (mat == 0) ? Wq : (mat == 1) ? Wk : (mat == 2) ? Wv : Wo;
  const int t = threadIdx.x;
#pragma unroll
  for (int i = 0; i < 16; ++i) {
    int idx = i * 256 + t;
    int r = idx >> 6, c = idx & 63;
    tile[r * 65 + c] = W[(size_t)(r0 + r) * DM + c0 + c];
  }
  __syncthreads();
#pragma unroll
  for (int i = 0; i < 16; ++i) {
    int idx = i * 256 + t;
    int r = idx >> 6, c = idx & 63;
    int n = c0 + r, kk = r0 + c;       // logical WT[n][k] = W[k][n]
    int n16 = n >> 4, ln = n & 15;
    int it = kk >> 5, h4 = (kk >> 3) & 3, e = kk & 7;
    int lane = h4 * 16 + ln;
    WTf[(size_t)mat * WSZ + ((size_t)(n16 * 16 + it) * 64 + lane) * 8 + e] =
        (f16)tile[c * 65 + r];
  }
}

// ---------- A-stationary projection (r13 winner, unchanged).
__global__ __launch_bounds__(512) void proj_kernel(
    const float* __restrict__ q, const float* __restrict__ k,
    const float* __restrict__ v, const f16* __restrict__ WTf,
    f16* __restrict__ Qf, f16* __restrict__ Kf, f16* __restrict__ Vf) {
  __shared__ f16 smA[32 * 512];   // 32 KB
  const int bid = blockIdx.x;
  const float* A;
  const f16* Bf;
  f16* C;
  int m0;
  if (bid < 128)      { A = q; Bf = WTf;            C = Qf; m0 = bid * 32; }
  else if (bid < 192) { A = k; Bf = WTf + WSZ;      C = Kf; m0 = (bid - 128) * 32; }
  else                { A = v; Bf = WTf + 2 * WSZ;  C = Vf; m0 = (bid - 192) * 32; }

  const int t = threadIdx.x;
  const int lane = t & 63;
  const int w = t >> 6;            // 0..7
  const int ln = lane & 15, hi4 = lane >> 4;
  const int rS = t >> 4;           // staging row 0..31
  const int kc = (t & 15) * 16;    // k chunk base (16 fp32) within a half

  // 1) issue B prefetch ring FIRST (L2 loads overlap the A HBM read)
  const f16* gB = Bf + ((size_t)(w * 4) * 16 * 64 + lane) * 8;
  f16x8 pb[4][4];
#pragma unroll
  for (int pp = 0; pp < 4; ++pp)
#pragma unroll
    for (int nf = 0; nf < 4; ++nf)
      pb[pp][nf] = *(const f16x8*)(gB + nf * 8192 + pp * 512);

  // 2) stage A half0 (k 0..255): thread loads 64 B of its row
  const float* gA = A + (size_t)(m0 + rS) * 512 + kc;
  {
    f32x4 x0 = *(const f32x4*)gA;
    f32x4 x1 = *(const f32x4*)(gA + 4);
    f32x4 x2 = *(const f32x4*)(gA + 8);
    f32x4 x3 = *(const f32x4*)(gA + 12);
    f16x8 h0, h1;
#pragma unroll
    for (int e = 0; e < 4; ++e) {
      h0[e] = (f16)x0[e]; h0[4 + e] = (f16)x1[e];
      h1[e] = (f16)x2[e]; h1[4 + e] = (f16)x3[e];
    }
    int u0 = kc >> 3, u1 = u0 + 1;
    int p0 = (u0 & ~7) | ((u0 & 7) ^ (rS & 7));
    int p1 = (u1 & ~7) | ((u1 & 7) ^ (rS & 7));
    *(f16x8*)&smA[rS * 512 + p0 * 8] = h0;
    *(f16x8*)&smA[rS * 512 + p1 * 8] = h1;
  }
  __syncthreads();

  // 3) issue A half1 loads (in flight during k-iters 0..7)
  f32x4 y0 = *(const f32x4*)(gA + 256);
  f32x4 y1 = *(const f32x4*)(gA + 260);
  f32x4 y2 = *(const f32x4*)(gA + 264);
  f32x4 y3 = *(const f32x4*)(gA + 268);

  const f32x4 zf = {0.f, 0.f, 0.f, 0.f};
  f32x4 acc[2][4];
#pragma unroll
  for (int a = 0; a < 2; ++a)
#pragma unroll
    for (int b = 0; b < 4; ++b) acc[a][b] = zf;

  // 4) k-iters 0..7 (units 0..31)
#pragma unroll
  for (int it = 0; it < 8; ++it) {
    const int slot = it & 3;
    f16x8 bfr[4], ah[2];
#pragma unroll
    for (int nf = 0; nf < 4; ++nf) bfr[nf] = pb[slot][nf];
#pragma unroll
    for (int nf = 0; nf < 4; ++nf)
      pb[slot][nf] = *(const f16x8*)(gB + nf * 8192 + (it + 4) * 512);
#pragma unroll
    for (int mf = 0; mf < 2; ++mf) {
      int row = mf * 16 + ln;
      int uu = it * 4 + hi4;
      int phys = (uu & ~7) | ((uu & 7) ^ (row & 7));
      ah[mf] = *(const f16x8*)&smA[row * 512 + phys * 8];
    }
#pragma unroll
    for (int mf = 0; mf < 2; ++mf)
#pragma unroll
      for (int nf = 0; nf < 4; ++nf)
        acc[mf][nf] = mfma_f16(ah[mf], bfr[nf], acc[mf][nf]);
  }

  // 5) write A half1 (units 32..63), barrier
  {
    f16x8 h2, h3;
#pragma unroll
    for (int e = 0; e < 4; ++e) {
      h2[e] = (f16)y0[e]; h2[4 + e] = (f16)y1[e];
      h3[e] = (f16)y2[e]; h3[4 + e] = (f16)y3[e];
    }
    int u0 = (kc >> 3) + 32, u1 = u0 + 1;
    int p0 = (u0 & ~7) | ((u0 & 7) ^ (rS & 7));
    int p1 = (u1 & ~7) | ((u1 & 7) ^ (rS & 7));
    *(f16x8*)&smA[rS * 512 + p0 * 8] = h2;
    *(f16x8*)&smA[rS * 512 + p1 * 8] = h3;
  }
  __syncthreads();

  // 6) k-iters 8..15
#pragma unroll
  for (int it = 8; it < 16; ++it) {
    const int slot = it & 3;
    f16x8 bfr[4], ah[2];
#pragma unroll
    for (int nf = 0; nf < 4; ++nf) bfr[nf] = pb[slot][nf];
    if (it + 4 < 16) {
#pragma unroll
      for (int nf = 0; nf < 4; ++nf)
        pb[slot][nf] = *(const f16x8*)(gB + nf * 8192 + (it + 4) * 512);
    }
#pragma unroll
    for (int mf = 0; mf < 2; ++mf) {
      int row = mf * 16 + ln;
      int uu = it * 4 + hi4;
      int phys = (uu & ~7) | ((uu & 7) ^ (row & 7));
      ah[mf] = *(const f16x8*)&smA[row * 512 + phys * 8];
    }
#pragma unroll
    for (int mf = 0; mf < 2; ++mf)
#pragma unroll
      for (int nf = 0; nf < 4; ++nf)
        acc[mf][nf] = mfma_f16(ah[mf], bfr[nf], acc[mf][nf]);
  }

#pragma unroll
  for (int mf = 0; mf < 2; ++mf)
#pragma unroll
    for (int nf = 0; nf < 4; ++nf)
#pragma unroll
      for (int e = 0; e < 4; ++e) {
        size_t off = (size_t)(m0 + mf * 16 + hi4 * 4 + e) * 512 +
                     w * 64 + nf * 16 + ln;
        C[off] = (f16)acc[mf][nf][e];
      }
}

// ---------- A-stationary output projection (r13 winner, unchanged).
__global__ __launch_bounds__(512) void outproj_kernel(
    const f16* __restrict__ AO, const f16* __restrict__ WTf,
    float* __restrict__ out) {
  __shared__ f16 smA[16 * 512];   // 16 KB
  const int bid = blockIdx.x;
  const int m0 = bid * 16;
  const f16* Bf = WTf + (size_t)3 * WSZ;
  const int t = threadIdx.x;
  const int lane = t & 63;
  const int w = t >> 6;
  const int ln = lane & 15, hi4 = lane >> 4;

  // 1) issue A loads into regs (HBM/L3 latency overlaps B-ring issue)
  f16x8 av[2];
  int rA[2], uA[2];
#pragma unroll
  for (int i = 0; i < 2; ++i) {
    int idx = i * 512 + t;
    rA[i] = idx >> 6; uA[i] = idx & 63;
    av[i] = *(const f16x8*)(AO + (size_t)(m0 + rA[i]) * 512 + uA[i] * 8);
  }

  // 2) issue B prefetch ring
  const f16* gB = Bf + ((size_t)(w * 4) * 16 * 64 + lane) * 8;
  f16x8 pb[4][4];
#pragma unroll
  for (int pp = 0; pp < 4; ++pp)
#pragma unroll
    for (int nf = 0; nf < 4; ++nf)
      pb[pp][nf] = *(const f16x8*)(gB + nf * 8192 + pp * 512);

  // 3) stage A to LDS, barrier
#pragma unroll
  for (int i = 0; i < 2; ++i) {
    int phys = (uA[i] & ~7) | ((uA[i] & 7) ^ (rA[i] & 7));
    *(f16x8*)&smA[rA[i] * 512 + phys * 8] = av[i];
  }
  __syncthreads();

  const f32x4 zf = {0.f, 0.f, 0.f, 0.f};
  f32x4 acc[4];
#pragma unroll
  for (int b = 0; b < 4; ++b) acc[b] = zf;

#pragma unroll
  for (int it = 0; it < 16; ++it) {
    const int slot = it & 3;
    f16x8 bfr[4], a8;
#pragma unroll
    for (int nf = 0; nf < 4; ++nf) bfr[nf] = pb[slot][nf];
    if (it + 4 < 16) {
#pragma unroll
      for (int nf = 0; nf < 4; ++nf)
        pb[slot][nf] = *(const f16x8*)(gB + nf * 8192 + (it + 4) * 512);
    }
    {
      int uu = it * 4 + hi4;
      int phys = (uu & ~7) | ((uu & 7) ^ (ln & 7));
      a8 = *(const f16x8*)&smA[ln * 512 + phys * 8];
    }
#pragma unroll
    for (int nf = 0; nf < 4; ++nf)
      acc[nf] = mfma_f16(a8, bfr[nf], acc[nf]);
  }

#pragma unroll
  for (int nf = 0; nf < 4; ++nf)
#pragma unroll
    for (int e = 0; e < 4; ++e)
      out[(size_t)(m0 + hi4 * 4 + e) * 512 + w * 64 + nf * 16 + ln] = acc[nf][e];
}

// ---------- banded attention: 64q x 96kv. LDS ALIASED: smP reuses the
// smQ+smK region (dead after QK^T; one barrier covers the WAR hazard).
// Footprint 52.25 -> 36.25 KB  =>  4 blocks/CU (__launch_bounds__(256,4)).
__global__ __launch_bounds__(256, 4) void attn_kernel(
    const f16* __restrict__ Qf, const f16* __restrict__ Kf,
    const f16* __restrict__ Vf, f16* __restrict__ AO) {
  __shared__ __align__(128) char smem[37120];
  f16* smQ  = (f16*)smem;             // [64][64]   8 KB   (dead after QK^T)
  f16* smK  = (f16*)(smem + 8192);    // [96][64]  12 KB   (dead after QK^T)
  f16* smVt = (f16*)(smem + 20480);   // [64][130] 16.25 KB
  f16* smP  = (f16*)smem;             // [64][128] 16 KB, ALIASES smQ/smK
  const int bid = blockIdx.x;
  const int qt = bid & 31;
  const int h  = (bid >> 5) & 7;
  const int b  = bid >> 8;
  const int j0 = qt * 64;
  const int pbase = (j0 >> 1) - 63;  // kv rows pbase..pbase+95
  const int t = threadIdx.x;
  const int lane = t & 63, w = t >> 6;   // 4 waves, 16 q-rows each
  const int ln = lane & 15, hi4 = lane >> 4;

#pragma unroll
  for (int i = 0; i < 2; ++i) {
    int idx = i * 256 + t;          // 512 units
    int r = idx >> 3, u = idx & 7;
    int sw = r * 64 + ((u ^ (r & 7)) * 8);
    size_t qoff = ((size_t)(b * LQn + j0 + r)) * 512 + h * 64 + u * 8;
    *(f16x8*)&smQ[sw] = *(const f16x8*)(Qf + qoff);
  }
#pragma unroll
  for (int i = 0; i < 3; ++i) {
    int idx = i * 256 + t;          // 768 units
    int r = idx >> 3, u = idx & 7;
    int sw = r * 64 + ((u ^ (r & 7)) * 8);
    int p = pbase + r;
    p = p < 0 ? 0 : (p > LKVn - 1 ? LKVn - 1 : p);  // clamped rows masked later
    size_t koff = ((size_t)(b * LKVn + p)) * 512 + h * 64 + u * 8;
    *(f16x8*)&smK[sw] = *(const f16x8*)(Kf + koff);
    f16x8 vv = *(const f16x8*)(Vf + koff);
#pragma unroll
    for (int e = 0; e < 8; ++e) {
      int rv = u * 8 + e;           // d-row of smVt
      smVt[rv * 130 + (((r >> 3) ^ (rv & 15)) * 8) + (r & 7)] = vv[e];
    }
  }
  __syncthreads();

  const f32x4 zf = {0.f, 0.f, 0.f, 0.f};
  f32x4 s[6];
#pragma unroll
  for (int cf = 0; cf < 6; ++cf) s[cf] = zf;
#pragma unroll
  for (int kk = 0; kk < 64; kk += 32) {
    const int ub = kk >> 3;
    int addrq = (w * 16 + ln) * 64 + (((ub + hi4) ^ (ln & 7)) * 8);
    f16x8 ah = *(const f16x8*)&smQ[addrq];
#pragma unroll
    for (int cf = 0; cf < 6; ++cf) {
      int addrk = (cf * 16 + ln) * 64 + (((ub + hi4) ^ (ln & 7)) * 8);
      f16x8 bh = *(const f16x8*)&smK[addrk];
      s[cf] = mfma_f16(ah, bh, s[cf]);
    }
  }
  __syncthreads();   // all QK^T reads of smQ/smK done before smP overwrites

#pragma unroll
  for (int r = 0; r < 4; ++r) {
    int rloc = w * 16 + hi4 * 4 + r;
    int wlo = rloc >> 1;
    int colmin = wlo > -pbase ? wlo : -pbase;
    int colmax = wlo + 63;
    float sv[6];
    float mx = -1e30f;
#pragma unroll
    for (int cf = 0; cf < 6; ++cf) {
      int col = cf * 16 + ln;
      float val = s[cf][r];
      bool ok = (col >= colmin) && (col <= colmax);
      sv[cf] = ok ? val : -1e30f;
      mx = fmaxf(mx, sv[cf]);
    }
#pragma unroll
    for (int msk = 1; msk < 16; msk <<= 1) mx = fmaxf(mx, __shfl_xor(mx, msk, 64));
    float sum = 0.f;
#pragma unroll
    for (int cf = 0; cf < 6; ++cf) {
      sv[cf] = __expf(sv[cf] - mx);
      sum += sv[cf];
    }
#pragma unroll
    for (int msk = 1; msk < 16; msk <<= 1) sum += __shfl_xor(sum, msk, 64);
    float rs = 1.0f / sum;
#pragma unroll
    for (int cf = 0; cf < 6; ++cf) {
      int uu = cf * 2 + (ln >> 3);
      smP[rloc * 128 + ((uu ^ (rloc & 15)) * 8) + (ln & 7)] = (f16)(sv[cf] * rs);
    }
  }
  __syncthreads();

  f32x4 o[4];
#pragma unroll
  for (int nf = 0; nf < 4; ++nf) o[nf] = zf;
#pragma unroll
  for (int kk = 0; kk < 96; kk += 32) {
    const int ub = kk >> 3;
    f16x8 pa = *(const f16x8*)&smP[(w * 16 + ln) * 128 + (((ub + hi4) ^ ln) * 8)];
#pragma unroll
    for (int nf = 0; nf < 4; ++nf) {
      int d = nf * 16 + ln;
      f16x8 vf = *(const f16x8*)&smVt[d * 130 + (((ub + hi4) ^ ln) * 8)];
      o[nf] = mfma_f16(pa, vf, o[nf]);
    }
  }

#pragma unroll
  for (int nf = 0; nf < 4; ++nf)
#pragma unroll
    for (int e = 0; e < 4; ++e) {
      int rloc = w * 16 + hi4 * 4 + e;
      AO[((size_t)(b * LQn + j0 + rloc)) * 512 + h * 64 + nf * 16 + ln] =
          (f16)o[nf][e];
    }
}

extern "C" void kernel_launch(void* const* d_in, const int* in_sizes, int n_in,
                              void* d_out, int out_size, void* d_ws, size_t ws_size,
                              hipStream_t stream) {
  const float* q    = (const float*)d_in[0];
  const float* k    = (const float*)d_in[1];
  const float* v    = (const float*)d_in[2];
  const float* Wq   = (const float*)d_in[3];
  const float* Wk   = (const float*)d_in[4];
  const float* Wv   = (const float*)d_in[5];
  const float* Wout = (const float*)d_in[6];
  float* out = (float*)d_out;

  char* ws = (char*)d_ws;
  f16* WTf = (f16*)ws;                          // 2 MB (fragment-packed)
  f16* Qf  = (f16*)(ws + (size_t)(2 << 20));    // 4 MB
  f16* Kf  = (f16*)(ws + (size_t)(6 << 20));    // 2 MB
  f16* Vf  = (f16*)(ws + (size_t)(8 << 20));    // 2 MB
  f16* AO  = (f16*)(ws + (size_t)(10 << 20));   // 4 MB  (total 14 MB)

  transpose_w_kernel<<<256, 256, 0, stream>>>(Wq, Wk, Wv, Wout, WTf);
  proj_kernel<<<256, 512, 0, stream>>>(q, k, v, WTf, Qf, Kf, Vf);
  attn_kernel<<<512, 256, 0, stream>>>(Qf, Kf, Vf, AO);
  outproj_kernel<<<256, 512, 0, stream>>>(AO, WTf, out);
}

// Round 17
// 38.245 us; speedup vs baseline: 1.0391x; 1.0391x over previous
//
#include <hip/hip_runtime.h>
#include <stdint.h>

typedef _Float16 f16;
typedef _Float16 f16x8 __attribute__((ext_vector_type(8)));
typedef float f32x4 __attribute__((ext_vector_type(4)));

#define LQn   2048
#define LKVn  1024
#define DM    512
#define NH    8
#define WSZ   262144   // f16 elems per packed weight matrix (512 KB)

static __device__ __forceinline__ f32x4 mfma_f16(f16x8 a, f16x8 b, f32x4 c) {
  return __builtin_amdgcn_mfma_f32_16x16x32_f16(a, b, c, 0, 0, 0);
}

// ---------- weight transpose + convert + FRAGMENT-PACK.
__global__ __launch_bounds__(256) void transpose_w_kernel(
    const float* __restrict__ Wq, const float* __restrict__ Wk,
    const float* __restrict__ Wv, const float* __restrict__ Wo,
    f16* __restrict__ WTf) {
  __shared__ float tile[64 * 65];
  const int bid = blockIdx.x;
  const int mat = bid >> 6;
  const int tb  = bid & 63;
  const int r0 = (tb >> 3) * 64;  // k block
  const int c0 = (tb & 7) * 64;   // n block
  const float* W = (mat == 0) ? Wq : (mat == 1) ? Wk : (mat == 2) ? Wv : Wo;
  const int t = threadIdx.x;
#pragma unroll
  for (int i = 0; i < 16; ++i) {
    int idx = i * 256 + t;
    int r = idx >> 6, c = idx & 63;
    tile[r * 65 + c] = W[(size_t)(r0 + r) * DM + c0 + c];
  }
  __syncthreads();
#pragma unroll
  for (int i = 0; i < 16; ++i) {
    int idx = i * 256 + t;
    int r = idx >> 6, c = idx & 63;
    int n = c0 + r, kk = r0 + c;       // logical WT[n][k] = W[k][n]
    int n16 = n >> 4, ln = n & 15;
    int it = kk >> 5, h4 = (kk >> 3) & 3, e = kk & 7;
    int lane = h4 * 16 + ln;
    WTf[(size_t)mat * WSZ + ((size_t)(n16 * 16 + it) * 64 + lane) * 8 + e] =
        (f16)tile[c * 65 + r];
  }
}

// ---------- A-stationary projection (32-row slabs, grid 256,
// B-ring issued first, half-k A-staging overlap).
__global__ __launch_bounds__(512) void proj_kernel(
    const float* __restrict__ q, const float* __restrict__ k,
    const float* __restrict__ v, const f16* __restrict__ WTf,
    f16* __restrict__ Qf, f16* __restrict__ Kf, f16* __restrict__ Vf) {
  __shared__ f16 smA[32 * 512];   // 32 KB
  const int bid = blockIdx.x;
  const float* A;
  const f16* Bf;
  f16* C;
  int m0;
  if (bid < 128)      { A = q; Bf = WTf;            C = Qf; m0 = bid * 32; }
  else if (bid < 192) { A = k; Bf = WTf + WSZ;      C = Kf; m0 = (bid - 128) * 32; }
  else                { A = v; Bf = WTf + 2 * WSZ;  C = Vf; m0 = (bid - 192) * 32; }

  const int t = threadIdx.x;
  const int lane = t & 63;
  const int w = t >> 6;            // 0..7
  const int ln = lane & 15, hi4 = lane >> 4;
  const int rS = t >> 4;           // staging row 0..31
  const int kc = (t & 15) * 16;    // k chunk base (16 fp32) within a half

  // 1) issue B prefetch ring FIRST (L2 loads overlap the A HBM read)
  const f16* gB = Bf + ((size_t)(w * 4) * 16 * 64 + lane) * 8;
  f16x8 pb[4][4];
#pragma unroll
  for (int pp = 0; pp < 4; ++pp)
#pragma unroll
    for (int nf = 0; nf < 4; ++nf)
      pb[pp][nf] = *(const f16x8*)(gB + nf * 8192 + pp * 512);

  // 2) stage A half0 (k 0..255): thread loads 64 B of its row
  const float* gA = A + (size_t)(m0 + rS) * 512 + kc;
  {
    f32x4 x0 = *(const f32x4*)gA;
    f32x4 x1 = *(const f32x4*)(gA + 4);
    f32x4 x2 = *(const f32x4*)(gA + 8);
    f32x4 x3 = *(const f32x4*)(gA + 12);
    f16x8 h0, h1;
#pragma unroll
    for (int e = 0; e < 4; ++e) {
      h0[e] = (f16)x0[e]; h0[4 + e] = (f16)x1[e];
      h1[e] = (f16)x2[e]; h1[4 + e] = (f16)x3[e];
    }
    int u0 = kc >> 3, u1 = u0 + 1;
    int p0 = (u0 & ~7) | ((u0 & 7) ^ (rS & 7));
    int p1 = (u1 & ~7) | ((u1 & 7) ^ (rS & 7));
    *(f16x8*)&smA[rS * 512 + p0 * 8] = h0;
    *(f16x8*)&smA[rS * 512 + p1 * 8] = h1;
  }
  __syncthreads();

  // 3) issue A half1 loads (in flight during k-iters 0..7)
  f32x4 y0 = *(const f32x4*)(gA + 256);
  f32x4 y1 = *(const f32x4*)(gA + 260);
  f32x4 y2 = *(const f32x4*)(gA + 264);
  f32x4 y3 = *(const f32x4*)(gA + 268);

  const f32x4 zf = {0.f, 0.f, 0.f, 0.f};
  f32x4 acc[2][4];
#pragma unroll
  for (int a = 0; a < 2; ++a)
#pragma unroll
    for (int b = 0; b < 4; ++b) acc[a][b] = zf;

  // 4) k-iters 0..7 (units 0..31)
#pragma unroll
  for (int it = 0; it < 8; ++it) {
    const int slot = it & 3;
    f16x8 bfr[4], ah[2];
#pragma unroll
    for (int nf = 0; nf < 4; ++nf) bfr[nf] = pb[slot][nf];
#pragma unroll
    for (int nf = 0; nf < 4; ++nf)
      pb[slot][nf] = *(const f16x8*)(gB + nf * 8192 + (it + 4) * 512);
#pragma unroll
    for (int mf = 0; mf < 2; ++mf) {
      int row = mf * 16 + ln;
      int uu = it * 4 + hi4;
      int phys = (uu & ~7) | ((uu & 7) ^ (row & 7));
      ah[mf] = *(const f16x8*)&smA[row * 512 + phys * 8];
    }
#pragma unroll
    for (int mf = 0; mf < 2; ++mf)
#pragma unroll
      for (int nf = 0; nf < 4; ++nf)
        acc[mf][nf] = mfma_f16(ah[mf], bfr[nf], acc[mf][nf]);
  }

  // 5) write A half1 (units 32..63), barrier
  {
    f16x8 h2, h3;
#pragma unroll
    for (int e = 0; e < 4; ++e) {
      h2[e] = (f16)y0[e]; h2[4 + e] = (f16)y1[e];
      h3[e] = (f16)y2[e]; h3[4 + e] = (f16)y3[e];
    }
    int u0 = (kc >> 3) + 32, u1 = u0 + 1;
    int p0 = (u0 & ~7) | ((u0 & 7) ^ (rS & 7));
    int p1 = (u1 & ~7) | ((u1 & 7) ^ (rS & 7));
    *(f16x8*)&smA[rS * 512 + p0 * 8] = h2;
    *(f16x8*)&smA[rS * 512 + p1 * 8] = h3;
  }
  __syncthreads();

  // 6) k-iters 8..15
#pragma unroll
  for (int it = 8; it < 16; ++it) {
    const int slot = it & 3;
    f16x8 bfr[4], ah[2];
#pragma unroll
    for (int nf = 0; nf < 4; ++nf) bfr[nf] = pb[slot][nf];
    if (it + 4 < 16) {
#pragma unroll
      for (int nf = 0; nf < 4; ++nf)
        pb[slot][nf] = *(const f16x8*)(gB + nf * 8192 + (it + 4) * 512);
    }
#pragma unroll
    for (int mf = 0; mf < 2; ++mf) {
      int row = mf * 16 + ln;
      int uu = it * 4 + hi4;
      int phys = (uu & ~7) | ((uu & 7) ^ (row & 7));
      ah[mf] = *(const f16x8*)&smA[row * 512 + phys * 8];
    }
#pragma unroll
    for (int mf = 0; mf < 2; ++mf)
#pragma unroll
      for (int nf = 0; nf < 4; ++nf)
        acc[mf][nf] = mfma_f16(ah[mf], bfr[nf], acc[mf][nf]);
  }

#pragma unroll
  for (int mf = 0; mf < 2; ++mf)
#pragma unroll
    for (int nf = 0; nf < 4; ++nf)
#pragma unroll
      for (int e = 0; e < 4; ++e) {
        size_t off = (size_t)(m0 + mf * 16 + hi4 * 4 + e) * 512 +
                     w * 64 + nf * 16 + ln;
        C[off] = (f16)acc[mf][nf][e];
      }
}

// ---------- A-stationary output projection (16-row, grid 256,
// A regs-first, B-ring overlap).
__global__ __launch_bounds__(512) void outproj_kernel(
    const f16* __restrict__ AO, const f16* __restrict__ WTf,
    float* __restrict__ out) {
  __shared__ f16 smA[16 * 512];   // 16 KB
  const int bid = blockIdx.x;
  const int m0 = bid * 16;
  const f16* Bf = WTf + (size_t)3 * WSZ;
  const int t = threadIdx.x;
  const int lane = t & 63;
  const int w = t >> 6;
  const int ln = lane & 15, hi4 = lane >> 4;

  // 1) issue A loads into regs (HBM/L3 latency overlaps B-ring issue)
  f16x8 av[2];
  int rA[2], uA[2];
#pragma unroll
  for (int i = 0; i < 2; ++i) {
    int idx = i * 512 + t;
    rA[i] = idx >> 6; uA[i] = idx & 63;
    av[i] = *(const f16x8*)(AO + (size_t)(m0 + rA[i]) * 512 + uA[i] * 8);
  }

  // 2) issue B prefetch ring
  const f16* gB = Bf + ((size_t)(w * 4) * 16 * 64 + lane) * 8;
  f16x8 pb[4][4];
#pragma unroll
  for (int pp = 0; pp < 4; ++pp)
#pragma unroll
    for (int nf = 0; nf < 4; ++nf)
      pb[pp][nf] = *(const f16x8*)(gB + nf * 8192 + pp * 512);

  // 3) stage A to LDS, barrier
#pragma unroll
  for (int i = 0; i < 2; ++i) {
    int phys = (uA[i] & ~7) | ((uA[i] & 7) ^ (rA[i] & 7));
    *(f16x8*)&smA[rA[i] * 512 + phys * 8] = av[i];
  }
  __syncthreads();

  const f32x4 zf = {0.f, 0.f, 0.f, 0.f};
  f32x4 acc[4];
#pragma unroll
  for (int b = 0; b < 4; ++b) acc[b] = zf;

#pragma unroll
  for (int it = 0; it < 16; ++it) {
    const int slot = it & 3;
    f16x8 bfr[4], a8;
#pragma unroll
    for (int nf = 0; nf < 4; ++nf) bfr[nf] = pb[slot][nf];
    if (it + 4 < 16) {
#pragma unroll
      for (int nf = 0; nf < 4; ++nf)
        pb[slot][nf] = *(const f16x8*)(gB + nf * 8192 + (it + 4) * 512);
    }
    {
      int uu = it * 4 + hi4;
      int phys = (uu & ~7) | ((uu & 7) ^ (ln & 7));
      a8 = *(const f16x8*)&smA[ln * 512 + phys * 8];
    }
#pragma unroll
    for (int nf = 0; nf < 4; ++nf)
      acc[nf] = mfma_f16(a8, bfr[nf], acc[nf]);
  }

#pragma unroll
  for (int nf = 0; nf < 4; ++nf)
#pragma unroll
    for (int e = 0; e < 4; ++e)
      out[(size_t)(m0 + hi4 * 4 + e) * 512 + w * 64 + nf * 16 + ln] = acc[nf][e];
}

// ---------- banded attention: 64q x 96kv, 2 blocks/CU; smVt stride 130.
__global__ __launch_bounds__(256, 2) void attn_kernel(
    const f16* __restrict__ Qf, const f16* __restrict__ Kf,
    const f16* __restrict__ Vf, f16* __restrict__ AO) {
  __shared__ f16 smQ[64 * 64];     // 8 KB
  __shared__ f16 smK[96 * 64];     // 12 KB
  __shared__ f16 smVt[64 * 130];   // 16.25 KB, [d][p<=96] swizzled, padded
  __shared__ f16 smP[64 * 128];    // 16 KB, swizzled
  const int bid = blockIdx.x;
  const int qt = bid & 31;
  const int h  = (bid >> 5) & 7;
  const int b  = bid >> 8;
  const int j0 = qt * 64;
  const int pbase = (j0 >> 1) - 63;  // kv rows pbase..pbase+95
  const int t = threadIdx.x;
  const int lane = t & 63, w = t >> 6;   // 4 waves, 16 q-rows each
  const int ln = lane & 15, hi4 = lane >> 4;

#pragma unroll
  for (int i = 0; i < 2; ++i) {
    int idx = i * 256 + t;          // 512 units
    int r = idx >> 3, u = idx & 7;
    int sw = r * 64 + ((u ^ (r & 7)) * 8);
    size_t qoff = ((size_t)(b * LQn + j0 + r)) * 512 + h * 64 + u * 8;
    *(f16x8*)&smQ[sw] = *(const f16x8*)(Qf + qoff);
  }
#pragma unroll
  for (int i = 0; i < 3; ++i) {
    int idx = i * 256 + t;          // 768 units
    int r = idx >> 3, u = idx & 7;
    int sw = r * 64 + ((u ^ (r & 7)) * 8);
    int p = pbase + r;
    p = p < 0 ? 0 : (p > LKVn - 1 ? LKVn - 1 : p);  // clamped rows masked later
    size_t koff = ((size_t)(b * LKVn + p)) * 512 + h * 64 + u * 8;
    *(f16x8*)&smK[sw] = *(const f16x8*)(Kf + koff);
    f16x8 vv = *(const f16x8*)(Vf + koff);
#pragma unroll
    for (int e = 0; e < 8; ++e) {
      int rv = u * 8 + e;           // d-row of smVt
      smVt[rv * 130 + (((r >> 3) ^ (rv & 15)) * 8) + (r & 7)] = vv[e];
    }
  }
  __syncthreads();

  const f32x4 zf = {0.f, 0.f, 0.f, 0.f};
  f32x4 s[6];
#pragma unroll
  for (int cf = 0; cf < 6; ++cf) s[cf] = zf;
#pragma unroll
  for (int kk = 0; kk < 64; kk += 32) {
    const int ub = kk >> 3;
    int addrq = (w * 16 + ln) * 64 + (((ub + hi4) ^ (ln & 7)) * 8);
    f16x8 ah = *(const f16x8*)&smQ[addrq];
#pragma unroll
    for (int cf = 0; cf < 6; ++cf) {
      int addrk = (cf * 16 + ln) * 64 + (((ub + hi4) ^ (ln & 7)) * 8);
      f16x8 bh = *(const f16x8*)&smK[addrk];
      s[cf] = mfma_f16(ah, bh, s[cf]);
    }
  }

#pragma unroll
  for (int r = 0; r < 4; ++r) {
    int rloc = w * 16 + hi4 * 4 + r;
    int wlo = rloc >> 1;
    int colmin = wlo > -pbase ? wlo : -pbase;
    int colmax = wlo + 63;
    float sv[6];
    float mx = -1e30f;
#pragma unroll
    for (int cf = 0; cf < 6; ++cf) {
      int col = cf * 16 + ln;
      float val = s[cf][r];
      bool ok = (col >= colmin) && (col <= colmax);
      sv[cf] = ok ? val : -1e30f;
      mx = fmaxf(mx, sv[cf]);
    }
#pragma unroll
    for (int msk = 1; msk < 16; msk <<= 1) mx = fmaxf(mx, __shfl_xor(mx, msk, 64));
    float sum = 0.f;
#pragma unroll
    for (int cf = 0; cf < 6; ++cf) {
      sv[cf] = __expf(sv[cf] - mx);
      sum += sv[cf];
    }
#pragma unroll
    for (int msk = 1; msk < 16; msk <<= 1) sum += __shfl_xor(sum, msk, 64);
    float rs = 1.0f / sum;
#pragma unroll
    for (int cf = 0; cf < 6; ++cf) {
      int uu = cf * 2 + (ln >> 3);
      smP[rloc * 128 + ((uu ^ (rloc & 15)) * 8) + (ln & 7)] = (f16)(sv[cf] * rs);
    }
  }
  __syncthreads();

  f32x4 o[4];
#pragma unroll
  for (int nf = 0; nf < 4; ++nf) o[nf] = zf;
#pragma unroll
  for (int kk = 0; kk < 96; kk += 32) {
    const int ub = kk >> 3;
    f16x8 pa = *(const f16x8*)&smP[(w * 16 + ln) * 128 + (((ub + hi4) ^ ln) * 8)];
#pragma unroll
    for (int nf = 0; nf < 4; ++nf) {
      int d = nf * 16 + ln;
      f16x8 vf = *(const f16x8*)&smVt[d * 130 + (((ub + hi4) ^ ln) * 8)];
      o[nf] = mfma_f16(pa, vf, o[nf]);
    }
  }

#pragma unroll
  for (int nf = 0; nf < 4; ++nf)
#pragma unroll
    for (int e = 0; e < 4; ++e) {
      int rloc = w * 16 + hi4 * 4 + e;
      AO[((size_t)(b * LQn + j0 + rloc)) * 512 + h * 64 + nf * 16 + ln] =
          (f16)o[nf][e];
    }
}

extern "C" void kernel_launch(void* const* d_in, const int* in_sizes, int n_in,
                              void* d_out, int out_size, void* d_ws, size_t ws_size,
                              hipStream_t stream) {
  const float* q    = (const float*)d_in[0];
  const float* k    = (const float*)d_in[1];
  const float* v    = (const float*)d_in[2];
  const float* Wq   = (const float*)d_in[3];
  const float* Wk   = (const float*)d_in[4];
  const float* Wv   = (const float*)d_in[5];
  const float* Wout = (const float*)d_in[6];
  float* out = (float*)d_out;

  char* ws = (char*)d_ws;
  f16* WTf = (f16*)ws;                          // 2 MB (fragment-packed)
  f16* Qf  = (f16*)(ws + (size_t)(2 << 20));    // 4 MB
  f16* Kf  = (f16*)(ws + (size_t)(6 << 20));    // 2 MB
  f16* Vf  = (f16*)(ws + (size_t)(8 << 20));    // 2 MB
  f16* AO  = (f16*)(ws + (size_t)(10 << 20));   // 4 MB  (total 14 MB)

  transpose_w_kernel<<<256, 256, 0, stream>>>(Wq, Wk, Wv, Wout, WTf);
  proj_kernel<<<256, 512, 0, stream>>>(q, k, v, WTf, Qf, Kf, Vf);
  attn_kernel<<<512, 256, 0, stream>>>(Qf, Kf, Vf, AO);
  outproj_kernel<<<256, 512, 0, stream>>>(AO, WTf, out);
}

// Round 18
// 37.654 us; speedup vs baseline: 1.0554x; 1.0157x over previous
//
#include <hip/hip_runtime.h>
#include <stdint.h>

typedef _Float16 f16;
typedef _Float16 f16x8 __attribute__((ext_vector_type(8)));
typedef float f32x4 __attribute__((ext_vector_type(4)));

#define LQn   2048
#define LKVn  1024
#define DM    512
#define NH    8
#define WSZ   262144   // f16 elems per packed weight matrix (512 KB)

static __device__ __forceinline__ f32x4 mfma_f16(f16x8 a, f16x8 b, f32x4 c) {
  return __builtin_amdgcn_mfma_f32_16x16x32_f16(a, b, c, 0, 0, 0);
}

// ---------- weight transpose + convert + FRAGMENT-PACK.
// Store phase VECTORIZED: each thread emits f16x8 (16B) units instead of
// 16 scalar 2B stores. Same values to the same addresses (e = k&7 is the
// fastest packed-address bit), so output is bit-identical.
__global__ __launch_bounds__(256) void transpose_w_kernel(
    const float* __restrict__ Wq, const float* __restrict__ Wk,
    const float* __restrict__ Wv, const float* __restrict__ Wo,
    f16* __restrict__ WTf) {
  __shared__ float tile[64 * 65];
  const int bid = blockIdx.x;
  const int mat = bid >> 6;
  const int tb  = bid & 63;
  const int r0 = (tb >> 3) * 64;  // k block
  const int c0 = (tb & 7) * 64;   // n block
  const float* W = (mat == 0) ? Wq : (mat == 1) ? Wk : (mat == 2) ? Wv : Wo;
  const int t = threadIdx.x;
#pragma unroll
  for (int i = 0; i < 16; ++i) {
    int idx = i * 256 + t;
    int r = idx >> 6, c = idx & 63;       // tile[k-local][n-local]
    tile[r * 65 + c] = W[(size_t)(r0 + r) * DM + c0 + c];
  }
  __syncthreads();
#pragma unroll
  for (int i = 0; i < 2; ++i) {
    int idx = i * 256 + t;                // 512 tasks: (n-local, k8)
    int rr  = idx & 63;                   // n-local (consecutive lanes)
    int k8  = idx >> 6;                   // 8-k group 0..7
    int n = c0 + rr;
    int kglob = r0 + k8 * 8;
    f16x8 hv;
#pragma unroll
    for (int e = 0; e < 8; ++e)
      hv[e] = (f16)tile[(k8 * 8 + e) * 65 + rr];
    int n16 = n >> 4, ln = n & 15;
    int it = kglob >> 5, h4 = (kglob >> 3) & 3;
    int lane = h4 * 16 + ln;
    *(f16x8*)&WTf[(size_t)mat * WSZ +
                  ((size_t)(n16 * 16 + it) * 64 + lane) * 8] = hv;
  }
}

// ---------- A-stationary projection (32-row slabs, grid 256,
// B-ring issued first, half-k A-staging overlap).
__global__ __launch_bounds__(512) void proj_kernel(
    const float* __restrict__ q, const float* __restrict__ k,
    const float* __restrict__ v, const f16* __restrict__ WTf,
    f16* __restrict__ Qf, f16* __restrict__ Kf, f16* __restrict__ Vf) {
  __shared__ f16 smA[32 * 512];   // 32 KB
  const int bid = blockIdx.x;
  const float* A;
  const f16* Bf;
  f16* C;
  int m0;
  if (bid < 128)      { A = q; Bf = WTf;            C = Qf; m0 = bid * 32; }
  else if (bid < 192) { A = k; Bf = WTf + WSZ;      C = Kf; m0 = (bid - 128) * 32; }
  else                { A = v; Bf = WTf + 2 * WSZ;  C = Vf; m0 = (bid - 192) * 32; }

  const int t = threadIdx.x;
  const int lane = t & 63;
  const int w = t >> 6;            // 0..7
  const int ln = lane & 15, hi4 = lane >> 4;
  const int rS = t >> 4;           // staging row 0..31
  const int kc = (t & 15) * 16;    // k chunk base (16 fp32) within a half

  // 1) issue B prefetch ring FIRST (L2 loads overlap the A HBM read)
  const f16* gB = Bf + ((size_t)(w * 4) * 16 * 64 + lane) * 8;
  f16x8 pb[4][4];
#pragma unroll
  for (int pp = 0; pp < 4; ++pp)
#pragma unroll
    for (int nf = 0; nf < 4; ++nf)
      pb[pp][nf] = *(const f16x8*)(gB + nf * 8192 + pp * 512);

  // 2) stage A half0 (k 0..255): thread loads 64 B of its row
  const float* gA = A + (size_t)(m0 + rS) * 512 + kc;
  {
    f32x4 x0 = *(const f32x4*)gA;
    f32x4 x1 = *(const f32x4*)(gA + 4);
    f32x4 x2 = *(const f32x4*)(gA + 8);
    f32x4 x3 = *(const f32x4*)(gA + 12);
    f16x8 h0, h1;
#pragma unroll
    for (int e = 0; e < 4; ++e) {
      h0[e] = (f16)x0[e]; h0[4 + e] = (f16)x1[e];
      h1[e] = (f16)x2[e]; h1[4 + e] = (f16)x3[e];
    }
    int u0 = kc >> 3, u1 = u0 + 1;
    int p0 = (u0 & ~7) | ((u0 & 7) ^ (rS & 7));
    int p1 = (u1 & ~7) | ((u1 & 7) ^ (rS & 7));
    *(f16x8*)&smA[rS * 512 + p0 * 8] = h0;
    *(f16x8*)&smA[rS * 512 + p1 * 8] = h1;
  }
  __syncthreads();

  // 3) issue A half1 loads (in flight during k-iters 0..7)
  f32x4 y0 = *(const f32x4*)(gA + 256);
  f32x4 y1 = *(const f32x4*)(gA + 260);
  f32x4 y2 = *(const f32x4*)(gA + 264);
  f32x4 y3 = *(const f32x4*)(gA + 268);

  const f32x4 zf = {0.f, 0.f, 0.f, 0.f};
  f32x4 acc[2][4];
#pragma unroll
  for (int a = 0; a < 2; ++a)
#pragma unroll
    for (int b = 0; b < 4; ++b) acc[a][b] = zf;

  // 4) k-iters 0..7 (units 0..31)
#pragma unroll
  for (int it = 0; it < 8; ++it) {
    const int slot = it & 3;
    f16x8 bfr[4], ah[2];
#pragma unroll
    for (int nf = 0; nf < 4; ++nf) bfr[nf] = pb[slot][nf];
#pragma unroll
    for (int nf = 0; nf < 4; ++nf)
      pb[slot][nf] = *(const f16x8*)(gB + nf * 8192 + (it + 4) * 512);
#pragma unroll
    for (int mf = 0; mf < 2; ++mf) {
      int row = mf * 16 + ln;
      int uu = it * 4 + hi4;
      int phys = (uu & ~7) | ((uu & 7) ^ (row & 7));
      ah[mf] = *(const f16x8*)&smA[row * 512 + phys * 8];
    }
#pragma unroll
    for (int mf = 0; mf < 2; ++mf)
#pragma unroll
      for (int nf = 0; nf < 4; ++nf)
        acc[mf][nf] = mfma_f16(ah[mf], bfr[nf], acc[mf][nf]);
  }

  // 5) write A half1 (units 32..63), barrier
  {
    f16x8 h2, h3;
#pragma unroll
    for (int e = 0; e < 4; ++e) {
      h2[e] = (f16)y0[e]; h2[4 + e] = (f16)y1[e];
      h3[e] = (f16)y2[e]; h3[4 + e] = (f16)y3[e];
    }
    int u0 = (kc >> 3) + 32, u1 = u0 + 1;
    int p0 = (u0 & ~7) | ((u0 & 7) ^ (rS & 7));
    int p1 = (u1 & ~7) | ((u1 & 7) ^ (rS & 7));
    *(f16x8*)&smA[rS * 512 + p0 * 8] = h2;
    *(f16x8*)&smA[rS * 512 + p1 * 8] = h3;
  }
  __syncthreads();

  // 6) k-iters 8..15
#pragma unroll
  for (int it = 8; it < 16; ++it) {
    const int slot = it & 3;
    f16x8 bfr[4], ah[2];
#pragma unroll
    for (int nf = 0; nf < 4; ++nf) bfr[nf] = pb[slot][nf];
    if (it + 4 < 16) {
#pragma unroll
      for (int nf = 0; nf < 4; ++nf)
        pb[slot][nf] = *(const f16x8*)(gB + nf * 8192 + (it + 4) * 512);
    }
#pragma unroll
    for (int mf = 0; mf < 2; ++mf) {
      int row = mf * 16 + ln;
      int uu = it * 4 + hi4;
      int phys = (uu & ~7) | ((uu & 7) ^ (row & 7));
      ah[mf] = *(const f16x8*)&smA[row * 512 + phys * 8];
    }
#pragma unroll
    for (int mf = 0; mf < 2; ++mf)
#pragma unroll
      for (int nf = 0; nf < 4; ++nf)
        acc[mf][nf] = mfma_f16(ah[mf], bfr[nf], acc[mf][nf]);
  }

#pragma unroll
  for (int mf = 0; mf < 2; ++mf)
#pragma unroll
    for (int nf = 0; nf < 4; ++nf)
#pragma unroll
      for (int e = 0; e < 4; ++e) {
        size_t off = (size_t)(m0 + mf * 16 + hi4 * 4 + e) * 512 +
                     w * 64 + nf * 16 + ln;
        C[off] = (f16)acc[mf][nf][e];
      }
}

// ---------- A-stationary output projection (16-row, grid 256,
// A regs-first, B-ring overlap).
__global__ __launch_bounds__(512) void outproj_kernel(
    const f16* __restrict__ AO, const f16* __restrict__ WTf,
    float* __restrict__ out) {
  __shared__ f16 smA[16 * 512];   // 16 KB
  const int bid = blockIdx.x;
  const int m0 = bid * 16;
  const f16* Bf = WTf + (size_t)3 * WSZ;
  const int t = threadIdx.x;
  const int lane = t & 63;
  const int w = t >> 6;
  const int ln = lane & 15, hi4 = lane >> 4;

  // 1) issue A loads into regs (HBM/L3 latency overlaps B-ring issue)
  f16x8 av[2];
  int rA[2], uA[2];
#pragma unroll
  for (int i = 0; i < 2; ++i) {
    int idx = i * 512 + t;
    rA[i] = idx >> 6; uA[i] = idx & 63;
    av[i] = *(const f16x8*)(AO + (size_t)(m0 + rA[i]) * 512 + uA[i] * 8);
  }

  // 2) issue B prefetch ring
  const f16* gB = Bf + ((size_t)(w * 4) * 16 * 64 + lane) * 8;
  f16x8 pb[4][4];
#pragma unroll
  for (int pp = 0; pp < 4; ++pp)
#pragma unroll
    for (int nf = 0; nf < 4; ++nf)
      pb[pp][nf] = *(const f16x8*)(gB + nf * 8192 + pp * 512);

  // 3) stage A to LDS, barrier
#pragma unroll
  for (int i = 0; i < 2; ++i) {
    int phys = (uA[i] & ~7) | ((uA[i] & 7) ^ (rA[i] & 7));
    *(f16x8*)&smA[rA[i] * 512 + phys * 8] = av[i];
  }
  __syncthreads();

  const f32x4 zf = {0.f, 0.f, 0.f, 0.f};
  f32x4 acc[4];
#pragma unroll
  for (int b = 0; b < 4; ++b) acc[b] = zf;

#pragma unroll
  for (int it = 0; it < 16; ++it) {
    const int slot = it & 3;
    f16x8 bfr[4], a8;
#pragma unroll
    for (int nf = 0; nf < 4; ++nf) bfr[nf] = pb[slot][nf];
    if (it + 4 < 16) {
#pragma unroll
      for (int nf = 0; nf < 4; ++nf)
        pb[slot][nf] = *(const f16x8*)(gB + nf * 8192 + (it + 4) * 512);
    }
    {
      int uu = it * 4 + hi4;
      int phys = (uu & ~7) | ((uu & 7) ^ (ln & 7));
      a8 = *(const f16x8*)&smA[ln * 512 + phys * 8];
    }
#pragma unroll
    for (int nf = 0; nf < 4; ++nf)
      acc[nf] = mfma_f16(a8, bfr[nf], acc[nf]);
  }

#pragma unroll
  for (int nf = 0; nf < 4; ++nf)
#pragma unroll
    for (int e = 0; e < 4; ++e)
      out[(size_t)(m0 + hi4 * 4 + e) * 512 + w * 64 + nf * 16 + ln] = acc[nf][e];
}

// ---------- banded attention: 64q x 96kv, 2 blocks/CU; smVt stride 130.
__global__ __launch_bounds__(256, 2) void attn_kernel(
    const f16* __restrict__ Qf, const f16* __restrict__ Kf,
    const f16* __restrict__ Vf, f16* __restrict__ AO) {
  __shared__ f16 smQ[64 * 64];     // 8 KB
  __shared__ f16 smK[96 * 64];     // 12 KB
  __shared__ f16 smVt[64 * 130];   // 16.25 KB, [d][p<=96] swizzled, padded
  __shared__ f16 smP[64 * 128];    // 16 KB, swizzled
  const int bid = blockIdx.x;
  const int qt = bid & 31;
  const int h  = (bid >> 5) & 7;
  const int b  = bid >> 8;
  const int j0 = qt * 64;
  const int pbase = (j0 >> 1) - 63;  // kv rows pbase..pbase+95
  const int t = threadIdx.x;
  const int lane = t & 63, w = t >> 6;   // 4 waves, 16 q-rows each
  const int ln = lane & 15, hi4 = lane >> 4;

#pragma unroll
  for (int i = 0; i < 2; ++i) {
    int idx = i * 256 + t;          // 512 units
    int r = idx >> 3, u = idx & 7;
    int sw = r * 64 + ((u ^ (r & 7)) * 8);
    size_t qoff = ((size_t)(b * LQn + j0 + r)) * 512 + h * 64 + u * 8;
    *(f16x8*)&smQ[sw] = *(const f16x8*)(Qf + qoff);
  }
#pragma unroll
  for (int i = 0; i < 3; ++i) {
    int idx = i * 256 + t;          // 768 units
    int r = idx >> 3, u = idx & 7;
    int sw = r * 64 + ((u ^ (r & 7)) * 8);
    int p = pbase + r;
    p = p < 0 ? 0 : (p > LKVn - 1 ? LKVn - 1 : p);  // clamped rows masked later
    size_t koff = ((size_t)(b * LKVn + p)) * 512 + h * 64 + u * 8;
    *(f16x8*)&smK[sw] = *(const f16x8*)(Kf + koff);
    f16x8 vv = *(const f16x8*)(Vf + koff);
#pragma unroll
    for (int e = 0; e < 8; ++e) {
      int rv = u * 8 + e;           // d-row of smVt
      smVt[rv * 130 + (((r >> 3) ^ (rv & 15)) * 8) + (r & 7)] = vv[e];
    }
  }
  __syncthreads();

  const f32x4 zf = {0.f, 0.f, 0.f, 0.f};
  f32x4 s[6];
#pragma unroll
  for (int cf = 0; cf < 6; ++cf) s[cf] = zf;
#pragma unroll
  for (int kk = 0; kk < 64; kk += 32) {
    const int ub = kk >> 3;
    int addrq = (w * 16 + ln) * 64 + (((ub + hi4) ^ (ln & 7)) * 8);
    f16x8 ah = *(const f16x8*)&smQ[addrq];
#pragma unroll
    for (int cf = 0; cf < 6; ++cf) {
      int addrk = (cf * 16 + ln) * 64 + (((ub + hi4) ^ (ln & 7)) * 8);
      f16x8 bh = *(const f16x8*)&smK[addrk];
      s[cf] = mfma_f16(ah, bh, s[cf]);
    }
  }

#pragma unroll
  for (int r = 0; r < 4; ++r) {
    int rloc = w * 16 + hi4 * 4 + r;
    int wlo = rloc >> 1;
    int colmin = wlo > -pbase ? wlo : -pbase;
    int colmax = wlo + 63;
    float sv[6];
    float mx = -1e30f;
#pragma unroll
    for (int cf = 0; cf < 6; ++cf) {
      int col = cf * 16 + ln;
      float val = s[cf][r];
      bool ok = (col >= colmin) && (col <= colmax);
      sv[cf] = ok ? val : -1e30f;
      mx = fmaxf(mx, sv[cf]);
    }
#pragma unroll
    for (int msk = 1; msk < 16; msk <<= 1) mx = fmaxf(mx, __shfl_xor(mx, msk, 64));
    float sum = 0.f;
#pragma unroll
    for (int cf = 0; cf < 6; ++cf) {
      sv[cf] = __expf(sv[cf] - mx);
      sum += sv[cf];
    }
#pragma unroll
    for (int msk = 1; msk < 16; msk <<= 1) sum += __shfl_xor(sum, msk, 64);
    float rs = 1.0f / sum;
#pragma unroll
    for (int cf = 0; cf < 6; ++cf) {
      int uu = cf * 2 + (ln >> 3);
      smP[rloc * 128 + ((uu ^ (rloc & 15)) * 8) + (ln & 7)] = (f16)(sv[cf] * rs);
    }
  }
  __syncthreads();

  f32x4 o[4];
#pragma unroll
  for (int nf = 0; nf < 4; ++nf) o[nf] = zf;
#pragma unroll
  for (int kk = 0; kk < 96; kk += 32) {
    const int ub = kk >> 3;
    f16x8 pa = *(const f16x8*)&smP[(w * 16 + ln) * 128 + (((ub + hi4) ^ ln) * 8)];
#pragma unroll
    for (int nf = 0; nf < 4; ++nf) {
      int d = nf * 16 + ln;
      f16x8 vf = *(const f16x8*)&smVt[d * 130 + (((ub + hi4) ^ ln) * 8)];
      o[nf] = mfma_f16(pa, vf, o[nf]);
    }
  }

#pragma unroll
  for (int nf = 0; nf < 4; ++nf)
#pragma unroll
    for (int e = 0; e < 4; ++e) {
      int rloc = w * 16 + hi4 * 4 + e;
      AO[((size_t)(b * LQn + j0 + rloc)) * 512 + h * 64 + nf * 16 + ln] =
          (f16)o[nf][e];
    }
}

extern "C" void kernel_launch(void* const* d_in, const int* in_sizes, int n_in,
                              void* d_out, int out_size, void* d_ws, size_t ws_size,
                              hipStream_t stream) {
  const float* q    = (const float*)d_in[0];
  const float* k    = (const float*)d_in[1];
  const float* v    = (const float*)d_in[2];
  const float* Wq   = (const float*)d_in[3];
  const float* Wk   = (const float*)d_in[4];
  const float* Wv   = (const float*)d_in[5];
  const float* Wout = (const float*)d_in[6];
  float* out = (float*)d_out;

  char* ws = (char*)d_ws;
  f16* WTf = (f16*)ws;                          // 2 MB (fragment-packed)
  f16* Qf  = (f16*)(ws + (size_t)(2 << 20));    // 4 MB
  f16* Kf  = (f16*)(ws + (size_t)(6 << 20));    // 2 MB
  f16* Vf  = (f16*)(ws + (size_t)(8 << 20));    // 2 MB
  f16* AO  = (f16*)(ws + (size_t)(10 << 20));   // 4 MB  (total 14 MB)

  transpose_w_kernel<<<256, 256, 0, stream>>>(Wq, Wk, Wv, Wout, WTf);
  proj_kernel<<<256, 512, 0, stream>>>(q, k, v, WTf, Qf, Kf, Vf);
  attn_kernel<<<512, 256, 0, stream>>>(Qf, Kf, Vf, AO);
  outproj_kernel<<<256, 512, 0, stream>>>(AO, WTf, out);
}